// Round 2
// baseline (30790.826 us; speedup 1.0000x reference)
//
#include <hip/hip_runtime.h>
#include <hip/hip_cooperative_groups.h>
#include <math.h>

namespace cg = cooperative_groups;

// DWM recurrent cell, cooperative version.
// Grid = 256 wgs x 1024 thr: wg = (batch b = blk>>2, column-slice = blk&3).
// Each wg holds a full replica of batch b's recurrent state (mem/wt/wtdyn) in
// LDS; replicas evolve identically (same deterministic fp ops, same inputs).
// Only the big matvec is sliced 4-way; state/upd slices are exchanged through
// a double-buffered global scratch with ONE grid.sync() per timestep.

#define NHEAD 4
#define MSZ   32
#define NADDR 256
#define SEQ   256
#define INDIM 264
#define SU    512
#define DB    256
#define UPDN  424
#define COMBN 904
#define HP    106
#define MEMP  257   // padded row stride (bank-conflict break)
#define WTP   257
#define NQ    300   // virtual col quads: 1192/4 = 298, padded to 300
#define QPS   75    // quads per slice (NQ/4)
#define KSL   13    // K-dim slices in matvec

__device__ __forceinline__ float sigmoidf_(float x) { return 1.0f / (1.0f + expf(-x)); }
__device__ __forceinline__ float softplusf_(float x) { return fmaxf(x, 0.0f) + log1pf(expf(-fabsf(x))); }

__global__ __launch_bounds__(1024) void dwm_kernel(
    const float* __restrict__ xin,
    const float* __restrict__ Wo, const float* __restrict__ bo,
    const float* __restrict__ Ws, const float* __restrict__ bs,
    const float* __restrict__ Wu, const float* __restrict__ bu,
    float* __restrict__ out,
    float* __restrict__ sbuf,    // [2][64][SU]   state exchange
    float* __restrict__ ubuf)    // [2][64][UPDN] upd exchange
{
    cg::grid_group grid = cg::this_grid();
    const int blk = blockIdx.x;
    const int slice = blk & 3;        // consecutive blks -> different slices; each
    const int b = blk >> 2;           // XCD's 32 wgs then share ONE weight slice
    const int tid = threadIdx.x;

    __shared__ float s_mem[MSZ * MEMP];
    __shared__ float s_wt[NHEAD * WTP];
    __shared__ float s_wtdyn[NHEAD * WTP];
    __shared__ union {
        float4 part4[KSL * QPS];                 // matvec partials (15.6 KB)
        float  part[KSL * QPS * 4];
        struct { float logit[NHEAD * WTP]; float wts[NHEAD * WTP]; } w;
    } u;
    __shared__ __align__(16) float s_comb[COMBN];
    __shared__ float s_read[NHEAD * MSZ];
    __shared__ float s_upd[UPDN];
    __shared__ float s_erase[NHEAD * MSZ];
    __shared__ float s_khat[NHEAD * MSZ];
    __shared__ float s_shift[NHEAD * 3], s_jmp[NHEAD * 3];
    __shared__ float s_jd[NHEAD], s_gamma[NHEAD], s_beta[NHEAD], s_g[NHEAD];
    __shared__ float s_smax[NHEAD], s_ssum[NHEAD], s_psum[NHEAD];

    // ---- init carry (each replica identically) ----
    {
        int h = tid >> 8, n = tid & 255;
        float v = (n == 0) ? 1.0f : 0.0f;
        s_wt[h * WTP + n] = v;
        s_wtdyn[h * WTP + n] = v;
    }
    for (int idx = tid; idx < MSZ * NADDR; idx += 1024) {
        int m = idx >> 8, n = idx & 255;
        s_mem[m * MEMP + n] = 0.01f;
    }
    __syncthreads();

    // matvec unit decode (ql fast within wave -> coalesced 1KB rows)
    const int mv_ks = tid / QPS;            // 0..13 (active if <13)
    const int mv_ql = tid - mv_ks * QPS;    // 0..74
    // K split in multiples of 4: first 5 slices 72 rows, rest 68 (5*72+8*68=904)
    const int mv_k0  = (mv_ks < 5) ? 72 * mv_ks : 360 + 68 * (mv_ks - 5);
    const int mv_nkq = (mv_ks < 5) ? 18 : 17;

    for (int t = 0; t < SEQ; ++t) {
        const int wb = t & 1;                 // write-parity this step
        const int rb = (t - 1) & 1;           // state read-parity (t>0)

        // ---- A: read[h][m] = sum_n wt[h][n] * mem[m][n] ----
        {
            int pair = tid >> 3, sub = tid & 7;
            int h = pair >> 5, m = pair & 31;
            float p = 0.0f;
            #pragma unroll 8
            for (int k = 0; k < 32; ++k) {
                int n = sub + (k << 3);
                p = fmaf(s_wt[h * WTP + n], s_mem[m * MEMP + n], p);
            }
            p += __shfl_down(p, 4);
            p += __shfl_down(p, 2);
            p += __shfl_down(p, 1);
            if (sub == 0) s_read[pair] = p;
        }
        __syncthreads();

        // ---- B: comb = [x_t | state | read] ----
        if (tid < INDIM)              s_comb[tid] = xin[((size_t)b * SEQ + t) * INDIM + tid];
        else if (tid < INDIM + SU)    s_comb[tid] = (t == 0) ? 1.0f : sbuf[((size_t)rb * 64 + b) * SU + (tid - INDIM)];
        else if (tid < COMBN)         s_comb[tid] = s_read[tid - (INDIM + SU)];
        __syncthreads();

        // ---- C: matvec slice: 75 quad-columns x 13 K-slices ----
        if (mv_ks < KSL) {
            int g = slice * QPS + mv_ql;     // global quad 0..299
            if (g < 298) {
                const float* W; int ncol, c;
                if (g < 128)      { W = Ws; ncol = SU;   c = g * 4; }
                else if (g < 192) { W = Wo; ncol = DB;   c = (g - 128) * 4; }
                else              { W = Wu; ncol = UPDN; c = (g - 192) * 4; }
                const float* wp = W + (size_t)mv_k0 * ncol + c;
                float ax = 0.f, ay = 0.f, az = 0.f, aw = 0.f;
                #pragma unroll 2
                for (int kq = 0; kq < mv_nkq; ++kq) {
                    float4 cb = *(const float4*)&s_comb[mv_k0 + (kq << 2)];
                    float4 w0 = *(const float4*)(wp);
                    float4 w1 = *(const float4*)(wp + ncol);
                    float4 w2 = *(const float4*)(wp + 2 * ncol);
                    float4 w3 = *(const float4*)(wp + 3 * ncol);
                    ax = fmaf(cb.x, w0.x, ax); ay = fmaf(cb.x, w0.y, ay);
                    az = fmaf(cb.x, w0.z, az); aw = fmaf(cb.x, w0.w, aw);
                    ax = fmaf(cb.y, w1.x, ax); ay = fmaf(cb.y, w1.y, ay);
                    az = fmaf(cb.y, w1.z, az); aw = fmaf(cb.y, w1.w, aw);
                    ax = fmaf(cb.z, w2.x, ax); ay = fmaf(cb.z, w2.y, ay);
                    az = fmaf(cb.z, w2.z, az); aw = fmaf(cb.z, w2.w, aw);
                    ax = fmaf(cb.w, w3.x, ax); ay = fmaf(cb.w, w3.y, ay);
                    az = fmaf(cb.w, w3.z, az); aw = fmaf(cb.w, w3.w, aw);
                    wp += 4 * ncol;
                }
                u.part4[mv_ks * QPS + mv_ql] = make_float4(ax, ay, az, aw);
            }
        }
        __syncthreads();

        // ---- D: reduce partials, activations, write slice outputs ----
        if (tid < 300) {
            int ql = tid >> 2, j = tid & 3;
            int g = slice * QPS + ql;
            if (g < 298) {
                float s = 0.0f;
                #pragma unroll
                for (int ks = 0; ks < KSL; ++ks) s += u.part[(ks * QPS + ql) * 4 + j];
                if (g < 128) {
                    int c = g * 4 + j;
                    sbuf[((size_t)wb * 64 + b) * SU + c] = sigmoidf_(s + bs[c]);
                } else if (g < 192) {
                    int c = (g - 128) * 4 + j;
                    out[((size_t)b * SEQ + t) * DB + c] = sigmoidf_(s + bo[c]);
                } else {
                    int c = (g - 192) * 4 + j;
                    ubuf[((size_t)wb * 64 + b) * UPDN + c] = s + bu[c];
                }
            }
        }
        __threadfence();
        grid.sync();

        // ---- E: gather full upd for this batch ----
        if (tid < UPDN) s_upd[tid] = ubuf[((size_t)wb * 64 + b) * UPDN + tid];
        __syncthreads();

        // ---- F: per-head parameter transforms ----
        if (tid < NHEAD * MSZ) {
            int h = tid >> 5, e = tid & 31;
            const float* uu = &s_upd[h * HP];
            s_erase[h * MSZ + e] = sigmoidf_(uu[8 + e]);
            float kv = tanhf(uu[72 + e]);
            float ss = kv * kv;
            ss += __shfl_xor(ss, 1);
            ss += __shfl_xor(ss, 2);
            ss += __shfl_xor(ss, 4);
            ss += __shfl_xor(ss, 8);
            ss += __shfl_xor(ss, 16);
            s_khat[h * MSZ + e] = kv / (sqrtf(ss) + 1e-12f);
        }
        if (tid < NHEAD) {
            const float* uu = &s_upd[tid * HP];
            float a0 = softplusf_(uu[0]), a1 = softplusf_(uu[1]), a2 = softplusf_(uu[2]);
            float mx = fmaxf(a0, fmaxf(a1, a2));
            float e0 = expf(a0 - mx), e1 = expf(a1 - mx), e2 = expf(a2 - mx);
            float inv = 1.0f / (e0 + e1 + e2);
            s_shift[tid * 3 + 0] = e0 * inv;
            s_shift[tid * 3 + 1] = e1 * inv;
            s_shift[tid * 3 + 2] = e2 * inv;
            s_jd[tid] = sigmoidf_(uu[3]);
            float j0 = uu[4], j1 = uu[5], j2 = uu[6];
            float jm = fmaxf(j0, fmaxf(j1, j2));
            float f0 = expf(j0 - jm), f1 = expf(j1 - jm), f2 = expf(j2 - jm);
            float jinv = 1.0f / (f0 + f1 + f2);
            s_jmp[tid * 3 + 0] = f0 * jinv;
            s_jmp[tid * 3 + 1] = f1 * jinv;
            s_jmp[tid * 3 + 2] = f2 * jinv;
            s_gamma[tid] = 1.0f + softplusf_(uu[7]);
            s_beta[tid] = softplusf_(uu[104]);
            s_g[tid] = sigmoidf_(uu[105]);
        }
        __syncthreads();

        // ---- G: memory erase/add (uses OLD wt) ----
        #pragma unroll
        for (int r = 0; r < 8; ++r) {
            int idx = tid + (r << 10);
            int m = idx >> 8, n = idx & 255;
            float w0 = s_wt[0 * WTP + n], w1 = s_wt[1 * WTP + n];
            float w2 = s_wt[2 * WTP + n], w3 = s_wt[3 * WTP + n];
            float prod = (1.0f - s_erase[0 * MSZ + m] * w0) * (1.0f - s_erase[1 * MSZ + m] * w1)
                       * (1.0f - s_erase[2 * MSZ + m] * w2) * (1.0f - s_erase[3 * MSZ + m] * w3);
            float addv = s_upd[0 * HP + 40 + m] * w0 + s_upd[1 * HP + 40 + m] * w1
                       + s_upd[2 * HP + 40 + m] * w2 + s_upd[3 * HP + 40 + m] * w3;
            s_mem[m * MEMP + n] = s_mem[m * MEMP + n] * prod + addv;
        }
        __syncthreads();

        // ---- H: content logits with fused column norm ----
        {
            int h = tid >> 8, n = tid & 255;
            float ss = 0.0f, d = 0.0f;
            #pragma unroll 8
            for (int m = 0; m < MSZ; ++m) {
                float v = s_mem[m * MEMP + n];
                ss = fmaf(v, v, ss);
                d = fmaf(s_khat[h * MSZ + m], v, d);
            }
            u.w.logit[h * WTP + n] = s_beta[h] * d / (sqrtf(ss) + 1e-12f);
        }
        __syncthreads();

        // ---- I: per-head softmax reduce ----
        if (tid < 256) {
            int h = tid >> 6, lane = tid & 63;
            float mx = -1e30f;
            #pragma unroll
            for (int k = 0; k < 4; ++k) mx = fmaxf(mx, u.w.logit[h * WTP + lane + (k << 6)]);
            for (int m2 = 32; m2 >= 1; m2 >>= 1) mx = fmaxf(mx, __shfl_xor(mx, m2));
            float sm = 0.0f;
            #pragma unroll
            for (int k = 0; k < 4; ++k) sm += expf(u.w.logit[h * WTP + lane + (k << 6)] - mx);
            for (int m2 = 32; m2 >= 1; m2 >>= 1) sm += __shfl_xor(sm, m2);
            if (lane == 0) { s_smax[h] = mx; s_ssum[h] = sm; }
        }
        __syncthreads();

        // ---- J: gate (computed 3x, fused) + circular conv + sharpen ----
        {
            int h = tid >> 8, n = tid & 255;
            float gg = s_g[h], om = 1.0f - gg;
            float inv = 1.0f / s_ssum[h], mx = s_smax[h];
            int nm = (n + 255) & 255, np = (n + 1) & 255;
            float wgm = gg * expf(u.w.logit[h * WTP + nm] - mx) * inv + om * s_wt[h * WTP + nm];
            float wg0 = gg * expf(u.w.logit[h * WTP + n ] - mx) * inv + om * s_wt[h * WTP + n ];
            float wgp = gg * expf(u.w.logit[h * WTP + np] - mx) * inv + om * s_wt[h * WTP + np];
            float v = s_shift[h * 3 + 0] * wgm + s_shift[h * 3 + 1] * wg0 + s_shift[h * 3 + 2] * wgp;
            u.w.wts[h * WTP + n] = powf(v + 1e-12f, s_gamma[h]);
        }
        __syncthreads();

        // ---- K: sharpen-normalizer reduce ----
        if (tid < 256) {
            int h = tid >> 6, lane = tid & 63;
            float sm = 0.0f;
            #pragma unroll
            for (int k = 0; k < 4; ++k) sm += u.w.wts[h * WTP + lane + (k << 6)];
            for (int m2 = 32; m2 >= 1; m2 >>= 1) sm += __shfl_xor(sm, m2);
            if (lane == 0) s_psum[h] = sm;
        }
        __syncthreads();

        // ---- L: snapshot + jump; new wt, wt_dyn ----
        {
            int h = tid >> 8, n = tid & 255;
            float ws_ = u.w.wts[h * WTP + n] / s_psum[h];
            float jd = s_jd[h];
            float dyn = (1.0f - jd) * s_wtdyn[h * WTP + n] + jd * ws_;
            s_wtdyn[h * WTP + n] = dyn;
            float w0v = (n == 0) ? 1.0f : 0.0f;
            s_wt[h * WTP + n] = s_jmp[h * 3 + 0] * ws_ + s_jmp[h * 3 + 1] * dyn + s_jmp[h * 3 + 2] * w0v;
        }
        __syncthreads();
    }
}

extern "C" void kernel_launch(void* const* d_in, const int* in_sizes, int n_in,
                              void* d_out, int out_size, void* d_ws, size_t ws_size,
                              hipStream_t stream) {
    const float* x  = (const float*)d_in[0];
    const float* Wo = (const float*)d_in[1];
    const float* bo = (const float*)d_in[2];
    const float* Ws = (const float*)d_in[3];
    const float* bs = (const float*)d_in[4];
    const float* Wu = (const float*)d_in[5];
    const float* bu = (const float*)d_in[6];
    float* outp = (float*)d_out;
    float* sbuf = (float*)d_ws;                 // 2*64*512 floats
    float* ubuf = sbuf + 2 * 64 * SU;           // 2*64*424 floats
    void* args[] = { (void*)&x, (void*)&Wo, (void*)&bo, (void*)&Ws, (void*)&bs,
                     (void*)&Wu, (void*)&bu, (void*)&outp, (void*)&sbuf, (void*)&ubuf };
    hipLaunchCooperativeKernel((const void*)dwm_kernel, dim3(256), dim3(1024),
                               args, 0, stream);
}

// Round 10
// 14429.900 us; speedup vs baseline: 2.1338x; 2.1338x over previous
//
#include <hip/hip_runtime.h>
#include <math.h>

// DWM recurrent cell. 64 wgs (1 per batch) x 1024 thr, no inter-wg sync.
// All recurrent state in LDS. Matvec restructured for memory-level
// parallelism: K-sliced quad-column decomposition, 16 dwordx4 loads in
// flight per lane, partials reduced in LDS.

#define NHEAD 4
#define MSZ   32
#define NADDR 256
#define SEQ   256
#define INDIM 264
#define SU    512
#define DB    256
#define UPDN  424
#define COMBN 904
#define HP    106
#define MEMP  257   // padded row stride (bank-conflict break)
#define WTP   257
#define NQ    298   // quad-columns: 1192/4
#define QL    300   // padded quad dimension for thread mapping
#define KSL   3     // K slices: 304,304,296

__device__ __forceinline__ float sigmoidf_(float x) { return 1.0f / (1.0f + expf(-x)); }
__device__ __forceinline__ float softplusf_(float x) { return fmaxf(x, 0.0f) + log1pf(expf(-fabsf(x))); }

__global__ __launch_bounds__(1024) void dwm_kernel(
    const float* __restrict__ xin,
    const float* __restrict__ Wo, const float* __restrict__ bo,
    const float* __restrict__ Ws, const float* __restrict__ bs,
    const float* __restrict__ Wu, const float* __restrict__ bu,
    float* __restrict__ out)
{
    const int b = blockIdx.x;
    const int tid = threadIdx.x;

    __shared__ float s_mem[MSZ * MEMP];
    __shared__ float s_wt[NHEAD * WTP];
    __shared__ float s_wtdyn[NHEAD * WTP];
    __shared__ union {
        float4 part4[KSL * QL];                  // matvec partials (14.4 KB)
        struct { float logit[NHEAD * WTP]; float wts[NHEAD * WTP]; } w;
    } u;
    __shared__ __align__(16) float s_comb[COMBN];
    __shared__ float s_state[SU];
    __shared__ float s_read[NHEAD * MSZ];
    __shared__ float s_upd[UPDN];
    __shared__ float s_erase[NHEAD * MSZ];
    __shared__ float s_khat[NHEAD * MSZ];
    __shared__ float s_shift[NHEAD * 3], s_jmp[NHEAD * 3];
    __shared__ float s_jd[NHEAD], s_gamma[NHEAD], s_beta[NHEAD], s_g[NHEAD];
    __shared__ float s_smax[NHEAD], s_ssum[NHEAD], s_psum[NHEAD];

    // ---- init carry ----
    if (tid < SU) s_state[tid] = 1.0f;
    {
        int h = tid >> 8, n = tid & 255;
        float v = (n == 0) ? 1.0f : 0.0f;
        s_wt[h * WTP + n] = v;
        s_wtdyn[h * WTP + n] = v;
    }
    for (int idx = tid; idx < MSZ * NADDR; idx += 1024) {
        int m = idx >> 8, n = idx & 255;
        s_mem[m * MEMP + n] = 0.01f;
    }
    __syncthreads();

    // ---- matvec thread decode (ql fast within wave -> coalesced rows) ----
    const int mv_ks = tid / QL;            // 0..3, active if <3
    const int mv_ql = tid - mv_ks * QL;    // 0..299, active if <298
    const int mv_k0 = 304 * mv_ks;         // 0,304,608
    const int mv_nit = (mv_ks < 2) ? 19 : 18;   // macro-iters of 16 rows
    const bool mv_act = (mv_ks < KSL) && (mv_ql < NQ);
    const float* mv_W; int mv_ncol, mv_c;
    if (mv_ql < 128)      { mv_W = Ws; mv_ncol = SU;   mv_c = mv_ql * 4; }
    else if (mv_ql < 192) { mv_W = Wo; mv_ncol = DB;   mv_c = (mv_ql - 128) * 4; }
    else                  { mv_W = Wu; mv_ncol = UPDN; mv_c = (mv_ql - 192) * 4; }

    for (int t = 0; t < SEQ; ++t) {
        // ---- A: read[h][m] = sum_n wt[h][n] * mem[m][n] ----
        {
            int pair = tid >> 3, sub = tid & 7;
            int h = pair >> 5, m = pair & 31;
            float p = 0.0f;
            #pragma unroll 8
            for (int k = 0; k < 32; ++k) {
                int n = sub + (k << 3);
                p = fmaf(s_wt[h * WTP + n], s_mem[m * MEMP + n], p);
            }
            p += __shfl_down(p, 4);
            p += __shfl_down(p, 2);
            p += __shfl_down(p, 1);
            if (sub == 0) s_read[pair] = p;
        }
        __syncthreads();

        // ---- B: comb = [x_t | state | read] ----
        if (tid < INDIM)              s_comb[tid] = xin[((size_t)b * SEQ + t) * INDIM + tid];
        else if (tid < INDIM + SU)    s_comb[tid] = s_state[tid - INDIM];
        else if (tid < COMBN)         s_comb[tid] = s_read[tid - (INDIM + SU)];
        __syncthreads();

        // ---- C: matvec, K-sliced quad columns, deep load pipeline ----
        if (mv_act) {
            const float* wp = mv_W + (size_t)mv_k0 * mv_ncol + mv_c;
            const int ncol = mv_ncol;
            float4 acc = make_float4(0.f, 0.f, 0.f, 0.f);
            int k = mv_k0;
            for (int it = 0; it < mv_nit; ++it) {
                #pragma unroll
                for (int uu = 0; uu < 4; ++uu) {
                    float4 cb = *(const float4*)&s_comb[k + (uu << 2)];
                    const float* w = wp + (size_t)uu * 4 * ncol;
                    float4 w0 = *(const float4*)(w);
                    float4 w1 = *(const float4*)(w + ncol);
                    float4 w2 = *(const float4*)(w + 2 * ncol);
                    float4 w3 = *(const float4*)(w + 3 * ncol);
                    acc.x = fmaf(cb.x, w0.x, acc.x); acc.y = fmaf(cb.x, w0.y, acc.y);
                    acc.z = fmaf(cb.x, w0.z, acc.z); acc.w = fmaf(cb.x, w0.w, acc.w);
                    acc.x = fmaf(cb.y, w1.x, acc.x); acc.y = fmaf(cb.y, w1.y, acc.y);
                    acc.z = fmaf(cb.y, w1.z, acc.z); acc.w = fmaf(cb.y, w1.w, acc.w);
                    acc.x = fmaf(cb.z, w2.x, acc.x); acc.y = fmaf(cb.z, w2.y, acc.y);
                    acc.z = fmaf(cb.z, w2.z, acc.z); acc.w = fmaf(cb.z, w2.w, acc.w);
                    acc.x = fmaf(cb.w, w3.x, acc.x); acc.y = fmaf(cb.w, w3.y, acc.y);
                    acc.z = fmaf(cb.w, w3.z, acc.z); acc.w = fmaf(cb.w, w3.w, acc.w);
                }
                wp += (size_t)16 * ncol;
                k += 16;
            }
            if (mv_ks == 2) {   // remainder rows 896..903
                #pragma unroll
                for (int uu = 0; uu < 2; ++uu) {
                    float4 cb = *(const float4*)&s_comb[k + (uu << 2)];
                    const float* w = wp + (size_t)uu * 4 * ncol;
                    float4 w0 = *(const float4*)(w);
                    float4 w1 = *(const float4*)(w + ncol);
                    float4 w2 = *(const float4*)(w + 2 * ncol);
                    float4 w3 = *(const float4*)(w + 3 * ncol);
                    acc.x = fmaf(cb.x, w0.x, acc.x); acc.y = fmaf(cb.x, w0.y, acc.y);
                    acc.z = fmaf(cb.x, w0.z, acc.z); acc.w = fmaf(cb.x, w0.w, acc.w);
                    acc.x = fmaf(cb.y, w1.x, acc.x); acc.y = fmaf(cb.y, w1.y, acc.y);
                    acc.z = fmaf(cb.y, w1.z, acc.z); acc.w = fmaf(cb.y, w1.w, acc.w);
                    acc.x = fmaf(cb.z, w2.x, acc.x); acc.y = fmaf(cb.z, w2.y, acc.y);
                    acc.z = fmaf(cb.z, w2.z, acc.z); acc.w = fmaf(cb.z, w2.w, acc.w);
                    acc.x = fmaf(cb.w, w3.x, acc.x); acc.y = fmaf(cb.w, w3.y, acc.y);
                    acc.z = fmaf(cb.w, w3.z, acc.z); acc.w = fmaf(cb.w, w3.w, acc.w);
                }
            }
            u.part4[mv_ks * QL + mv_ql] = acc;
        }
        __syncthreads();

        // ---- D: reduce partials + bias + activation, route outputs ----
        // NOTE: 1192 virtual outputs > 1024 threads -> strided loop (R6 bugfix:
        // `if (tid < 1192)` left s_upd[256..423] (heads 2-3 params) unwritten).
        for (int v = tid; v < SU + DB + UPDN; v += 1024) {
            int ql = v >> 2, j = v & 3;
            const float* p = (const float*)u.part4;
            float s = p[(0 * QL + ql) * 4 + j] + p[(1 * QL + ql) * 4 + j] + p[(2 * QL + ql) * 4 + j];
            if (v < SU) {
                s_state[v] = sigmoidf_(s + bs[v]);
            } else if (v < SU + DB) {
                int c = v - SU;
                out[((size_t)b * SEQ + t) * DB + c] = sigmoidf_(s + bo[c]);
            } else {
                int c = v - (SU + DB);
                s_upd[c] = s + bu[c];
            }
        }
        __syncthreads();

        // ---- F: per-head parameter transforms ----
        if (tid < NHEAD * MSZ) {
            int h = tid >> 5, e = tid & 31;
            const float* uu = &s_upd[h * HP];
            s_erase[h * MSZ + e] = sigmoidf_(uu[8 + e]);
            float kv = tanhf(uu[72 + e]);
            float ss = kv * kv;
            ss += __shfl_xor(ss, 1);
            ss += __shfl_xor(ss, 2);
            ss += __shfl_xor(ss, 4);
            ss += __shfl_xor(ss, 8);
            ss += __shfl_xor(ss, 16);
            s_khat[h * MSZ + e] = kv / (sqrtf(ss) + 1e-12f);
        }
        if (tid < NHEAD) {
            const float* uu = &s_upd[tid * HP];
            float a0 = softplusf_(uu[0]), a1 = softplusf_(uu[1]), a2 = softplusf_(uu[2]);
            float mx = fmaxf(a0, fmaxf(a1, a2));
            float e0 = expf(a0 - mx), e1 = expf(a1 - mx), e2 = expf(a2 - mx);
            float inv = 1.0f / (e0 + e1 + e2);
            s_shift[tid * 3 + 0] = e0 * inv;
            s_shift[tid * 3 + 1] = e1 * inv;
            s_shift[tid * 3 + 2] = e2 * inv;
            s_jd[tid] = sigmoidf_(uu[3]);
            float j0 = uu[4], j1 = uu[5], j2 = uu[6];
            float jm = fmaxf(j0, fmaxf(j1, j2));
            float f0 = expf(j0 - jm), f1 = expf(j1 - jm), f2 = expf(j2 - jm);
            float jinv = 1.0f / (f0 + f1 + f2);
            s_jmp[tid * 3 + 0] = f0 * jinv;
            s_jmp[tid * 3 + 1] = f1 * jinv;
            s_jmp[tid * 3 + 2] = f2 * jinv;
            s_gamma[tid] = 1.0f + softplusf_(uu[7]);
            s_beta[tid] = softplusf_(uu[104]);
            s_g[tid] = sigmoidf_(uu[105]);
        }
        __syncthreads();

        // ---- G: memory erase/add (uses OLD wt) ----
        #pragma unroll
        for (int r = 0; r < 8; ++r) {
            int idx = tid + (r << 10);
            int m = idx >> 8, n = idx & 255;
            float w0 = s_wt[0 * WTP + n], w1 = s_wt[1 * WTP + n];
            float w2 = s_wt[2 * WTP + n], w3 = s_wt[3 * WTP + n];
            float prod = (1.0f - s_erase[0 * MSZ + m] * w0) * (1.0f - s_erase[1 * MSZ + m] * w1)
                       * (1.0f - s_erase[2 * MSZ + m] * w2) * (1.0f - s_erase[3 * MSZ + m] * w3);
            float addv = s_upd[0 * HP + 40 + m] * w0 + s_upd[1 * HP + 40 + m] * w1
                       + s_upd[2 * HP + 40 + m] * w2 + s_upd[3 * HP + 40 + m] * w3;
            s_mem[m * MEMP + n] = s_mem[m * MEMP + n] * prod + addv;
        }
        __syncthreads();

        // ---- H: content logits with fused column norm ----
        {
            int h = tid >> 8, n = tid & 255;
            float ss = 0.0f, d = 0.0f;
            #pragma unroll 8
            for (int m = 0; m < MSZ; ++m) {
                float v = s_mem[m * MEMP + n];
                ss = fmaf(v, v, ss);
                d = fmaf(s_khat[h * MSZ + m], v, d);
            }
            u.w.logit[h * WTP + n] = s_beta[h] * d / (sqrtf(ss) + 1e-12f);
        }
        __syncthreads();

        // ---- I: per-head softmax reduce ----
        if (tid < 256) {
            int h = tid >> 6, lane = tid & 63;
            float mx = -1e30f;
            #pragma unroll
            for (int k = 0; k < 4; ++k) mx = fmaxf(mx, u.w.logit[h * WTP + lane + (k << 6)]);
            for (int m2 = 32; m2 >= 1; m2 >>= 1) mx = fmaxf(mx, __shfl_xor(mx, m2));
            float sm = 0.0f;
            #pragma unroll
            for (int k = 0; k < 4; ++k) sm += expf(u.w.logit[h * WTP + lane + (k << 6)] - mx);
            for (int m2 = 32; m2 >= 1; m2 >>= 1) sm += __shfl_xor(sm, m2);
            if (lane == 0) { s_smax[h] = mx; s_ssum[h] = sm; }
        }
        __syncthreads();

        // ---- J: gate (recomputed 3x, fused) + circular conv + sharpen ----
        {
            int h = tid >> 8, n = tid & 255;
            float gg = s_g[h], om = 1.0f - gg;
            float inv = 1.0f / s_ssum[h], mx = s_smax[h];
            int nm = (n + 255) & 255, np = (n + 1) & 255;
            float wgm = gg * expf(u.w.logit[h * WTP + nm] - mx) * inv + om * s_wt[h * WTP + nm];
            float wg0 = gg * expf(u.w.logit[h * WTP + n ] - mx) * inv + om * s_wt[h * WTP + n ];
            float wgp = gg * expf(u.w.logit[h * WTP + np] - mx) * inv + om * s_wt[h * WTP + np];
            float v = s_shift[h * 3 + 0] * wgm + s_shift[h * 3 + 1] * wg0 + s_shift[h * 3 + 2] * wgp;
            u.w.wts[h * WTP + n] = powf(v + 1e-12f, s_gamma[h]);
        }
        __syncthreads();

        // ---- K: sharpen-normalizer reduce ----
        if (tid < 256) {
            int h = tid >> 6, lane = tid & 63;
            float sm = 0.0f;
            #pragma unroll
            for (int k = 0; k < 4; ++k) sm += u.w.wts[h * WTP + lane + (k << 6)];
            for (int m2 = 32; m2 >= 1; m2 >>= 1) sm += __shfl_xor(sm, m2);
            if (lane == 0) s_psum[h] = sm;
        }
        __syncthreads();

        // ---- L: snapshot + jump; new wt, wt_dyn ----
        {
            int h = tid >> 8, n = tid & 255;
            float ws_ = u.w.wts[h * WTP + n] / s_psum[h];
            float jd = s_jd[h];
            float dyn = (1.0f - jd) * s_wtdyn[h * WTP + n] + jd * ws_;
            s_wtdyn[h * WTP + n] = dyn;
            float w0v = (n == 0) ? 1.0f : 0.0f;
            s_wt[h * WTP + n] = s_jmp[h * 3 + 0] * ws_ + s_jmp[h * 3 + 1] * dyn + s_jmp[h * 3 + 2] * w0v;
        }
        __syncthreads();
    }
}

extern "C" void kernel_launch(void* const* d_in, const int* in_sizes, int n_in,
                              void* d_out, int out_size, void* d_ws, size_t ws_size,
                              hipStream_t stream) {
    const float* x  = (const float*)d_in[0];
    const float* Wo = (const float*)d_in[1];
    const float* bo = (const float*)d_in[2];
    const float* Ws = (const float*)d_in[3];
    const float* bs = (const float*)d_in[4];
    const float* Wu = (const float*)d_in[5];
    const float* bu = (const float*)d_in[6];
    float* outp = (float*)d_out;
    hipLaunchKernelGGL(dwm_kernel, dim3(64), dim3(1024), 0, stream,
                       x, Wo, bo, Ws, bs, Wu, bu, outp);
}

// Round 11
// 12511.977 us; speedup vs baseline: 2.4609x; 1.1533x over previous
//
#include <hip/hip_runtime.h>
#include <hip/hip_fp16.h>
#include <math.h>

// DWM recurrent cell. 64 wgs (1 per batch) x 1024 thr, no inter-wg sync.
// All recurrent state in LDS. R10 change: weights packed to fp16 in d_ws by a
// pre-kernel each launch -> 2.16 MB fits per-XCD L2 (fp32 4.31 MB did not),
// halving bytes and making the per-step weight stream L2-resident.

#define NHEAD 4
#define MSZ   32
#define NADDR 256
#define SEQ   256
#define INDIM 264
#define SU    512
#define DB    256
#define UPDN  424
#define COMBN 904
#define HP    106
#define MEMP  257   // padded row stride (bank-conflict break)
#define WTP   257
#define NQ    298   // quad-columns: 1192/4
#define QL    300   // padded quad dimension for thread mapping
#define KSL   3     // K slices: 304,304,296

// fp16 weight blob layout in d_ws (half indices)
#define HWS_OFF 0
#define HWO_OFF 462848              // 904*512
#define HWU_OFF 694272              // + 904*256
#define HW_TOT  1077568             // + 904*424
#define PACK_G4 (HW_TOT / 4)        // float4 groups to convert

__device__ __forceinline__ float sigmoidf_(float x) { return 1.0f / (1.0f + expf(-x)); }
__device__ __forceinline__ float softplusf_(float x) { return fmaxf(x, 0.0f) + log1pf(expf(-fabsf(x))); }

__device__ __forceinline__ float4 h4_to_f4(uint2 u) {
    float2 a = __half22float2(*(__half2*)&u.x);
    float2 b = __half22float2(*(__half2*)&u.y);
    return make_float4(a.x, a.y, b.x, b.y);
}

// ---- pre-pass: convert [Ws|Wo|Wu] fp32 -> fp16 blob in d_ws ----
__global__ __launch_bounds__(256) void pack_w(
    const float* __restrict__ Ws, const float* __restrict__ Wo,
    const float* __restrict__ Wu, __half* __restrict__ dst)
{
    int g = blockIdx.x * 256 + threadIdx.x;
    if (g >= PACK_G4) return;
    const int T1 = HWO_OFF / 4, T2 = HWU_OFF / 4;
    const float* src; int off;
    if (g < T1)      { src = Ws; off = g * 4; }
    else if (g < T2) { src = Wo; off = (g - T1) * 4; }
    else             { src = Wu; off = (g - T2) * 4; }
    float4 v = *(const float4*)(src + off);
    __half2 a = __floats2half2_rn(v.x, v.y);
    __half2 b = __floats2half2_rn(v.z, v.w);
    *(__half2*)(dst + (size_t)g * 4)     = a;
    *(__half2*)(dst + (size_t)g * 4 + 2) = b;
}

__global__ __launch_bounds__(1024, 4) void dwm_kernel(
    const float* __restrict__ xin,
    const __half* __restrict__ hW,
    const float* __restrict__ bo, const float* __restrict__ bs,
    const float* __restrict__ bu,
    float* __restrict__ out)
{
    const int b = blockIdx.x;
    const int tid = threadIdx.x;

    __shared__ float s_mem[MSZ * MEMP];
    __shared__ float s_wt[NHEAD * WTP];
    __shared__ float s_wtdyn[NHEAD * WTP];
    __shared__ union {
        float4 part4[KSL * QL];                  // matvec partials (14.4 KB)
        struct { float logit[NHEAD * WTP]; float wts[NHEAD * WTP]; } w;
    } u;
    __shared__ __align__(16) float s_comb[COMBN];
    __shared__ float s_state[SU];
    __shared__ float s_read[NHEAD * MSZ];
    __shared__ float s_upd[UPDN];
    __shared__ float s_erase[NHEAD * MSZ];
    __shared__ float s_khat[NHEAD * MSZ];
    __shared__ float s_shift[NHEAD * 3], s_jmp[NHEAD * 3];
    __shared__ float s_jd[NHEAD], s_gamma[NHEAD], s_beta[NHEAD], s_g[NHEAD];
    __shared__ float s_smax[NHEAD], s_ssum[NHEAD], s_psum[NHEAD];

    // ---- init carry ----
    if (tid < SU) s_state[tid] = 1.0f;
    {
        int h = tid >> 8, n = tid & 255;
        float v = (n == 0) ? 1.0f : 0.0f;
        s_wt[h * WTP + n] = v;
        s_wtdyn[h * WTP + n] = v;
    }
    for (int idx = tid; idx < MSZ * NADDR; idx += 1024) {
        int m = idx >> 8, n = idx & 255;
        s_mem[m * MEMP + n] = 0.01f;
    }
    __syncthreads();

    // ---- matvec thread decode (ql fast within wave -> coalesced rows) ----
    const int mv_ks = tid / QL;            // 0..3, active if <3
    const int mv_ql = tid - mv_ks * QL;    // 0..299, active if <298
    const int mv_k0 = 304 * mv_ks;         // 0,304,608
    const int mv_nit = (mv_ks < 2) ? 19 : 18;   // macro-iters of 16 rows
    const bool mv_act = (mv_ks < KSL) && (mv_ql < NQ);
    const __half* mv_W; int mv_ncol, mv_c;
    if (mv_ql < 128)      { mv_W = hW + HWS_OFF; mv_ncol = SU;   mv_c = mv_ql * 4; }
    else if (mv_ql < 192) { mv_W = hW + HWO_OFF; mv_ncol = DB;   mv_c = (mv_ql - 128) * 4; }
    else                  { mv_W = hW + HWU_OFF; mv_ncol = UPDN; mv_c = (mv_ql - 192) * 4; }

    for (int t = 0; t < SEQ; ++t) {
        // ---- A: read[h][m] = sum_n wt[h][n] * mem[m][n] ----
        {
            int pair = tid >> 3, sub = tid & 7;
            int h = pair >> 5, m = pair & 31;
            float p = 0.0f;
            #pragma unroll 8
            for (int k = 0; k < 32; ++k) {
                int n = sub + (k << 3);
                p = fmaf(s_wt[h * WTP + n], s_mem[m * MEMP + n], p);
            }
            p += __shfl_down(p, 4);
            p += __shfl_down(p, 2);
            p += __shfl_down(p, 1);
            if (sub == 0) s_read[pair] = p;
        }
        __syncthreads();

        // ---- B: comb = [x_t | state | read] ----
        if (tid < INDIM)              s_comb[tid] = xin[((size_t)b * SEQ + t) * INDIM + tid];
        else if (tid < INDIM + SU)    s_comb[tid] = s_state[tid - INDIM];
        else if (tid < COMBN)         s_comb[tid] = s_read[tid - (INDIM + SU)];
        __syncthreads();

        // ---- C: matvec, K-sliced quad columns, fp16 weights (L2-resident) ----
        if (mv_act) {
            const __half* wp = mv_W + (size_t)mv_k0 * mv_ncol + mv_c;
            const int ncol = mv_ncol;
            float4 acc = make_float4(0.f, 0.f, 0.f, 0.f);
            int k = mv_k0;
            for (int it = 0; it < mv_nit; ++it) {
                #pragma unroll
                for (int uu = 0; uu < 4; ++uu) {
                    float4 cb = *(const float4*)&s_comb[k + (uu << 2)];
                    const __half* w = wp + (size_t)uu * 4 * ncol;
                    uint2 u0 = *(const uint2*)(w);
                    uint2 u1 = *(const uint2*)(w + ncol);
                    uint2 u2 = *(const uint2*)(w + 2 * ncol);
                    uint2 u3 = *(const uint2*)(w + 3 * ncol);
                    float4 w0 = h4_to_f4(u0), w1 = h4_to_f4(u1);
                    float4 w2 = h4_to_f4(u2), w3 = h4_to_f4(u3);
                    acc.x = fmaf(cb.x, w0.x, acc.x); acc.y = fmaf(cb.x, w0.y, acc.y);
                    acc.z = fmaf(cb.x, w0.z, acc.z); acc.w = fmaf(cb.x, w0.w, acc.w);
                    acc.x = fmaf(cb.y, w1.x, acc.x); acc.y = fmaf(cb.y, w1.y, acc.y);
                    acc.z = fmaf(cb.y, w1.z, acc.z); acc.w = fmaf(cb.y, w1.w, acc.w);
                    acc.x = fmaf(cb.z, w2.x, acc.x); acc.y = fmaf(cb.z, w2.y, acc.y);
                    acc.z = fmaf(cb.z, w2.z, acc.z); acc.w = fmaf(cb.z, w2.w, acc.w);
                    acc.x = fmaf(cb.w, w3.x, acc.x); acc.y = fmaf(cb.w, w3.y, acc.y);
                    acc.z = fmaf(cb.w, w3.z, acc.z); acc.w = fmaf(cb.w, w3.w, acc.w);
                }
                wp += (size_t)16 * ncol;
                k += 16;
            }
            if (mv_ks == 2) {   // remainder rows 896..903
                #pragma unroll
                for (int uu = 0; uu < 2; ++uu) {
                    float4 cb = *(const float4*)&s_comb[k + (uu << 2)];
                    const __half* w = wp + (size_t)uu * 4 * ncol;
                    uint2 u0 = *(const uint2*)(w);
                    uint2 u1 = *(const uint2*)(w + ncol);
                    uint2 u2 = *(const uint2*)(w + 2 * ncol);
                    uint2 u3 = *(const uint2*)(w + 3 * ncol);
                    float4 w0 = h4_to_f4(u0), w1 = h4_to_f4(u1);
                    float4 w2 = h4_to_f4(u2), w3 = h4_to_f4(u3);
                    acc.x = fmaf(cb.x, w0.x, acc.x); acc.y = fmaf(cb.x, w0.y, acc.y);
                    acc.z = fmaf(cb.x, w0.z, acc.z); acc.w = fmaf(cb.x, w0.w, acc.w);
                    acc.x = fmaf(cb.y, w1.x, acc.x); acc.y = fmaf(cb.y, w1.y, acc.y);
                    acc.z = fmaf(cb.y, w1.z, acc.z); acc.w = fmaf(cb.y, w1.w, acc.w);
                    acc.x = fmaf(cb.z, w2.x, acc.x); acc.y = fmaf(cb.z, w2.y, acc.y);
                    acc.z = fmaf(cb.z, w2.z, acc.z); acc.w = fmaf(cb.z, w2.w, acc.w);
                    acc.x = fmaf(cb.w, w3.x, acc.x); acc.y = fmaf(cb.w, w3.y, acc.y);
                    acc.z = fmaf(cb.w, w3.z, acc.z); acc.w = fmaf(cb.w, w3.w, acc.w);
                }
            }
            u.part4[mv_ks * QL + mv_ql] = acc;
        }
        __syncthreads();

        // ---- D: reduce partials + bias + activation, route outputs ----
        // strided: 1192 virtual outputs > 1024 threads (R6 bugfix)
        for (int v = tid; v < SU + DB + UPDN; v += 1024) {
            int ql = v >> 2, j = v & 3;
            const float* p = (const float*)u.part4;
            float s = p[(0 * QL + ql) * 4 + j] + p[(1 * QL + ql) * 4 + j] + p[(2 * QL + ql) * 4 + j];
            if (v < SU) {
                s_state[v] = sigmoidf_(s + bs[v]);
            } else if (v < SU + DB) {
                int c = v - SU;
                out[((size_t)b * SEQ + t) * DB + c] = sigmoidf_(s + bo[c]);
            } else {
                int c = v - (SU + DB);
                s_upd[c] = s + bu[c];
            }
        }
        __syncthreads();

        // ---- F: per-head parameter transforms ----
        if (tid < NHEAD * MSZ) {
            int h = tid >> 5, e = tid & 31;
            const float* uu = &s_upd[h * HP];
            s_erase[h * MSZ + e] = sigmoidf_(uu[8 + e]);
            float kv = tanhf(uu[72 + e]);
            float ss = kv * kv;
            ss += __shfl_xor(ss, 1);
            ss += __shfl_xor(ss, 2);
            ss += __shfl_xor(ss, 4);
            ss += __shfl_xor(ss, 8);
            ss += __shfl_xor(ss, 16);
            s_khat[h * MSZ + e] = kv / (sqrtf(ss) + 1e-12f);
        }
        if (tid < NHEAD) {
            const float* uu = &s_upd[tid * HP];
            float a0 = softplusf_(uu[0]), a1 = softplusf_(uu[1]), a2 = softplusf_(uu[2]);
            float mx = fmaxf(a0, fmaxf(a1, a2));
            float e0 = expf(a0 - mx), e1 = expf(a1 - mx), e2 = expf(a2 - mx);
            float inv = 1.0f / (e0 + e1 + e2);
            s_shift[tid * 3 + 0] = e0 * inv;
            s_shift[tid * 3 + 1] = e1 * inv;
            s_shift[tid * 3 + 2] = e2 * inv;
            s_jd[tid] = sigmoidf_(uu[3]);
            float j0 = uu[4], j1 = uu[5], j2 = uu[6];
            float jm = fmaxf(j0, fmaxf(j1, j2));
            float f0 = expf(j0 - jm), f1 = expf(j1 - jm), f2 = expf(j2 - jm);
            float jinv = 1.0f / (f0 + f1 + f2);
            s_jmp[tid * 3 + 0] = f0 * jinv;
            s_jmp[tid * 3 + 1] = f1 * jinv;
            s_jmp[tid * 3 + 2] = f2 * jinv;
            s_gamma[tid] = 1.0f + softplusf_(uu[7]);
            s_beta[tid] = softplusf_(uu[104]);
            s_g[tid] = sigmoidf_(uu[105]);
        }
        __syncthreads();

        // ---- G: memory erase/add (uses OLD wt) ----
        #pragma unroll
        for (int r = 0; r < 8; ++r) {
            int idx = tid + (r << 10);
            int m = idx >> 8, n = idx & 255;
            float w0 = s_wt[0 * WTP + n], w1 = s_wt[1 * WTP + n];
            float w2 = s_wt[2 * WTP + n], w3 = s_wt[3 * WTP + n];
            float prod = (1.0f - s_erase[0 * MSZ + m] * w0) * (1.0f - s_erase[1 * MSZ + m] * w1)
                       * (1.0f - s_erase[2 * MSZ + m] * w2) * (1.0f - s_erase[3 * MSZ + m] * w3);
            float addv = s_upd[0 * HP + 40 + m] * w0 + s_upd[1 * HP + 40 + m] * w1
                       + s_upd[2 * HP + 40 + m] * w2 + s_upd[3 * HP + 40 + m] * w3;
            s_mem[m * MEMP + n] = s_mem[m * MEMP + n] * prod + addv;
        }
        __syncthreads();

        // ---- H: content logits with fused column norm ----
        {
            int h = tid >> 8, n = tid & 255;
            float ss = 0.0f, d = 0.0f;
            #pragma unroll 8
            for (int m = 0; m < MSZ; ++m) {
                float v = s_mem[m * MEMP + n];
                ss = fmaf(v, v, ss);
                d = fmaf(s_khat[h * MSZ + m], v, d);
            }
            u.w.logit[h * WTP + n] = s_beta[h] * d / (sqrtf(ss) + 1e-12f);
        }
        __syncthreads();

        // ---- I: per-head softmax reduce ----
        if (tid < 256) {
            int h = tid >> 6, lane = tid & 63;
            float mx = -1e30f;
            #pragma unroll
            for (int k = 0; k < 4; ++k) mx = fmaxf(mx, u.w.logit[h * WTP + lane + (k << 6)]);
            for (int m2 = 32; m2 >= 1; m2 >>= 1) mx = fmaxf(mx, __shfl_xor(mx, m2));
            float sm = 0.0f;
            #pragma unroll
            for (int k = 0; k < 4; ++k) sm += expf(u.w.logit[h * WTP + lane + (k << 6)] - mx);
            for (int m2 = 32; m2 >= 1; m2 >>= 1) sm += __shfl_xor(sm, m2);
            if (lane == 0) { s_smax[h] = mx; s_ssum[h] = sm; }
        }
        __syncthreads();

        // ---- J: gate (recomputed 3x, fused) + circular conv + sharpen ----
        {
            int h = tid >> 8, n = tid & 255;
            float gg = s_g[h], om = 1.0f - gg;
            float inv = 1.0f / s_ssum[h], mx = s_smax[h];
            int nm = (n + 255) & 255, np = (n + 1) & 255;
            float wgm = gg * expf(u.w.logit[h * WTP + nm] - mx) * inv + om * s_wt[h * WTP + nm];
            float wg0 = gg * expf(u.w.logit[h * WTP + n ] - mx) * inv + om * s_wt[h * WTP + n ];
            float wgp = gg * expf(u.w.logit[h * WTP + np] - mx) * inv + om * s_wt[h * WTP + np];
            float v = s_shift[h * 3 + 0] * wgm + s_shift[h * 3 + 1] * wg0 + s_shift[h * 3 + 2] * wgp;
            u.w.wts[h * WTP + n] = powf(v + 1e-12f, s_gamma[h]);
        }
        __syncthreads();

        // ---- K: sharpen-normalizer reduce ----
        if (tid < 256) {
            int h = tid >> 6, lane = tid & 63;
            float sm = 0.0f;
            #pragma unroll
            for (int k = 0; k < 4; ++k) sm += u.w.wts[h * WTP + lane + (k << 6)];
            for (int m2 = 32; m2 >= 1; m2 >>= 1) sm += __shfl_xor(sm, m2);
            if (lane == 0) s_psum[h] = sm;
        }
        __syncthreads();

        // ---- L: snapshot + jump; new wt, wt_dyn ----
        {
            int h = tid >> 8, n = tid & 255;
            float ws_ = u.w.wts[h * WTP + n] / s_psum[h];
            float jd = s_jd[h];
            float dyn = (1.0f - jd) * s_wtdyn[h * WTP + n] + jd * ws_;
            s_wtdyn[h * WTP + n] = dyn;
            float w0v = (n == 0) ? 1.0f : 0.0f;
            s_wt[h * WTP + n] = s_jmp[h * 3 + 0] * ws_ + s_jmp[h * 3 + 1] * dyn + s_jmp[h * 3 + 2] * w0v;
        }
        __syncthreads();
    }
}

extern "C" void kernel_launch(void* const* d_in, const int* in_sizes, int n_in,
                              void* d_out, int out_size, void* d_ws, size_t ws_size,
                              hipStream_t stream) {
    const float* x  = (const float*)d_in[0];
    const float* Wo = (const float*)d_in[1];
    const float* bo = (const float*)d_in[2];
    const float* Ws = (const float*)d_in[3];
    const float* bs = (const float*)d_in[4];
    const float* Wu = (const float*)d_in[5];
    const float* bu = (const float*)d_in[6];
    float* outp = (float*)d_out;
    __half* hW = (__half*)d_ws;   // 2,155,136 bytes

    int pack_blocks = (PACK_G4 + 255) / 256;
    hipLaunchKernelGGL(pack_w, dim3(pack_blocks), dim3(256), 0, stream, Ws, Wo, Wu, hW);
    hipLaunchKernelGGL(dwm_kernel, dim3(64), dim3(1024), 0, stream,
                       x, (const __half*)hW, bo, bs, bu, outp);
}

// Round 13
// 7685.253 us; speedup vs baseline: 4.0065x; 1.6281x over previous
//
#include <hip/hip_runtime.h>
#include <hip/hip_fp16.h>
#include <math.h>

// DWM recurrent cell. 64 wgs (1 per batch) x 1024 thr, no inter-wg sync.
// R11: fp16 weights in d_ws (L2-resident). R12: matvec re-tiled for half the
// load count + deep pipeline: 8-col ownership, uint4 (16B) loads, explicit
// 4-row prefetch; LDS moved to one dynamic 78.8 KB blob; phase-A bank remap.

#define NHEAD 4
#define MSZ   32
#define NADDR 256
#define SEQ   256
#define INDIM 264
#define SU    512
#define DB    256
#define UPDN  424
#define COMBN 904
#define HP    106
#define MEMP  257   // padded row stride (bank-conflict break)
#define WTP   257
#define NOC   149   // octo-columns: 1192/8
#define KSL   6     // K slices: 152x5 + 144 (all /4)
#define NOUT  1192

// fp16 weight blob layout in d_ws (half indices)
#define HWS_OFF 0
#define HWO_OFF 462848              // 904*512
#define HWU_OFF 694272              // + 904*256
#define HW_TOT  1077568             // + 904*424
#define PACK_G4 (HW_TOT / 4)

// dynamic LDS layout (float offsets)
#define O_MEM    0                  // 32*257  = 8224
#define O_WT     8224               // 4*257   = 1028
#define O_WTDYN  9252               // 4*257   = 1028
#define O_PART   10280              // 6*1192  = 7152 (overlaid by logit/wts)
#define O_COMB   17432              // 904
#define O_STATE  18336              // 512
#define O_READ   18848              // 128
#define O_UPD    18976              // 424
#define O_ERASE  19400              // 128
#define O_KHAT   19528              // 128
#define O_SHIFT  19656              // 12
#define O_JMP    19668              // 12
#define O_JD     19680
#define O_GAMMA  19684
#define O_BETA   19688
#define O_G      19692
#define O_SMAX   19696
#define O_SSUM   19700
#define O_PSUM   19704
#define SMEM_FLOATS 19708           // 78,832 bytes

__device__ __forceinline__ float sigmoidf_(float x) { return 1.0f / (1.0f + expf(-x)); }
__device__ __forceinline__ float softplusf_(float x) { return fmaxf(x, 0.0f) + log1pf(expf(-fabsf(x))); }

// ---- pre-pass: convert [Ws|Wo|Wu] fp32 -> fp16 blob in d_ws ----
__global__ __launch_bounds__(256) void pack_w(
    const float* __restrict__ Ws, const float* __restrict__ Wo,
    const float* __restrict__ Wu, __half* __restrict__ dst)
{
    int g = blockIdx.x * 256 + threadIdx.x;
    if (g >= PACK_G4) return;
    const int T1 = HWO_OFF / 4, T2 = HWU_OFF / 4;
    const float* src; int off;
    if (g < T1)      { src = Ws; off = g * 4; }
    else if (g < T2) { src = Wo; off = (g - T1) * 4; }
    else             { src = Wu; off = (g - T2) * 4; }
    float4 v = *(const float4*)(src + off);
    __half2 a = __floats2half2_rn(v.x, v.y);
    __half2 b = __floats2half2_rn(v.z, v.w);
    *(__half2*)(dst + (size_t)g * 4)     = a;
    *(__half2*)(dst + (size_t)g * 4 + 2) = b;
}

#define FMA8(P, C) { float c_ = (C); \
    float2 f0_ = __half22float2(*(const __half2*)&(P).x); \
    float2 f1_ = __half22float2(*(const __half2*)&(P).y); \
    float2 f2_ = __half22float2(*(const __half2*)&(P).z); \
    float2 f3_ = __half22float2(*(const __half2*)&(P).w); \
    a0 = fmaf(c_, f0_.x, a0); a1 = fmaf(c_, f0_.y, a1); \
    a2 = fmaf(c_, f1_.x, a2); a3 = fmaf(c_, f1_.y, a3); \
    a4 = fmaf(c_, f2_.x, a4); a5 = fmaf(c_, f2_.y, a5); \
    a6 = fmaf(c_, f3_.x, a6); a7 = fmaf(c_, f3_.y, a7); }

__global__ __launch_bounds__(1024, 4) void dwm_kernel(
    const float* __restrict__ xin,
    const __half* __restrict__ hW,
    const float* __restrict__ bo, const float* __restrict__ bs,
    const float* __restrict__ bu,
    float* __restrict__ out)
{
    const int b = blockIdx.x;
    const int tid = threadIdx.x;

    extern __shared__ float smem[];
    float* s_mem   = smem + O_MEM;
    float* s_wt    = smem + O_WT;
    float* s_wtdyn = smem + O_WTDYN;
    float* s_part  = smem + O_PART;
    float* s_logit = smem + O_PART;          // overlays s_part (post-D phases)
    float* s_wts   = smem + O_PART + 1028;
    float* s_comb  = smem + O_COMB;
    float* s_state = smem + O_STATE;
    float* s_read  = smem + O_READ;
    float* s_upd   = smem + O_UPD;
    float* s_erase = smem + O_ERASE;
    float* s_khat  = smem + O_KHAT;
    float* s_shift = smem + O_SHIFT;
    float* s_jmp   = smem + O_JMP;
    float* s_jd    = smem + O_JD;
    float* s_gamma = smem + O_GAMMA;
    float* s_beta  = smem + O_BETA;
    float* s_g     = smem + O_G;
    float* s_smax  = smem + O_SMAX;
    float* s_ssum  = smem + O_SSUM;
    float* s_psum  = smem + O_PSUM;

    // ---- init carry ----
    if (tid < SU) s_state[tid] = 1.0f;
    {
        int h = tid >> 8, n = tid & 255;
        float v = (n == 0) ? 1.0f : 0.0f;
        s_wt[h * WTP + n] = v;
        s_wtdyn[h * WTP + n] = v;
    }
    for (int idx = tid; idx < MSZ * NADDR; idx += 1024) {
        int m = idx >> 8, n = idx & 255;
        s_mem[m * MEMP + n] = 0.01f;
    }
    __syncthreads();

    // ---- matvec thread decode: tid = ks*149 + oc (oc fast -> coalesced) ----
    const int mv_ks = tid / NOC;            // 0..6, active if <6
    const int mv_oc = tid - mv_ks * NOC;    // 0..148
    const bool mv_act = (mv_ks < KSL);
    const int mv_k0 = 152 * mv_ks;          // 0,152,...,760
    const int mv_nit = (mv_ks < 5) ? 38 : 36;   // row-quads in slice
    const __half* mv_W; int mv_ncol, mv_c;
    if (mv_oc < 64)       { mv_W = hW + HWS_OFF; mv_ncol = SU;   mv_c = mv_oc * 8; }
    else if (mv_oc < 96)  { mv_W = hW + HWO_OFF; mv_ncol = DB;   mv_c = (mv_oc - 64) * 8; }
    else                  { mv_W = hW + HWU_OFF; mv_ncol = UPDN; mv_c = (mv_oc - 96) * 8; }

    for (int t = 0; t < SEQ; ++t) {
        // ---- A: read[h][m] = sum_n wt[h][n] * mem[m][n] (bank-spread m) ----
        {
            int pair = tid >> 3, sub = tid & 7;
            int h = pair >> 5, pp = pair & 31;
            int m = ((pp & 7) << 2) | (pp >> 3);   // bijective; wave's m-set stride-4
            float p = 0.0f;
            #pragma unroll 8
            for (int k = 0; k < 32; ++k) {
                int n = sub + (k << 3);
                p = fmaf(s_wt[h * WTP + n], s_mem[m * MEMP + n], p);
            }
            p += __shfl_down(p, 4);
            p += __shfl_down(p, 2);
            p += __shfl_down(p, 1);
            if (sub == 0) s_read[h * MSZ + m] = p;
        }
        __syncthreads();

        // ---- B: comb = [x_t | state | read] ----
        if (tid < INDIM)              s_comb[tid] = xin[((size_t)b * SEQ + t) * INDIM + tid];
        else if (tid < INDIM + SU)    s_comb[tid] = s_state[tid - INDIM];
        else if (tid < COMBN)         s_comb[tid] = s_read[tid - (INDIM + SU)];
        __syncthreads();

        // ---- C: matvec, 8-col x K-slice, uint4 loads, 4-row prefetch ----
        if (mv_act) {
            const __half* wp = mv_W + (size_t)mv_k0 * mv_ncol + mv_c;
            const int stride = mv_ncol;
            float a0=0.f,a1=0.f,a2=0.f,a3=0.f,a4=0.f,a5=0.f,a6=0.f,a7=0.f;
            uint4 p0 = *(const uint4*)(wp);
            uint4 p1 = *(const uint4*)(wp + stride);
            uint4 p2 = *(const uint4*)(wp + 2 * stride);
            uint4 p3 = *(const uint4*)(wp + 3 * stride);
            wp += 4 * stride;
            int k = mv_k0;
            for (int it = 0; it < mv_nit - 1; ++it) {
                uint4 n0 = *(const uint4*)(wp);
                uint4 n1 = *(const uint4*)(wp + stride);
                uint4 n2 = *(const uint4*)(wp + 2 * stride);
                uint4 n3 = *(const uint4*)(wp + 3 * stride);
                wp += 4 * stride;
                float4 cb = *(const float4*)&s_comb[k];
                FMA8(p0, cb.x); FMA8(p1, cb.y); FMA8(p2, cb.z); FMA8(p3, cb.w);
                k += 4;
                p0 = n0; p1 = n1; p2 = n2; p3 = n3;
            }
            float4 cb = *(const float4*)&s_comb[k];
            FMA8(p0, cb.x); FMA8(p1, cb.y); FMA8(p2, cb.z); FMA8(p3, cb.w);
            float* dst = s_part + mv_ks * NOUT + mv_oc * 8;
            *(float4*)dst       = make_float4(a0, a1, a2, a3);
            *(float4*)(dst + 4) = make_float4(a4, a5, a6, a7);
        }
        __syncthreads();

        // ---- D: reduce 6 partials + bias + activation, route outputs ----
        for (int v = tid; v < NOUT; v += 1024) {
            float s = s_part[v] + s_part[NOUT + v] + s_part[2 * NOUT + v]
                    + s_part[3 * NOUT + v] + s_part[4 * NOUT + v] + s_part[5 * NOUT + v];
            if (v < SU) {
                s_state[v] = sigmoidf_(s + bs[v]);
            } else if (v < SU + DB) {
                int c = v - SU;
                out[((size_t)b * SEQ + t) * DB + c] = sigmoidf_(s + bo[c]);
            } else {
                int c = v - (SU + DB);
                s_upd[c] = s + bu[c];
            }
        }
        __syncthreads();

        // ---- F: per-head parameter transforms ----
        if (tid < NHEAD * MSZ) {
            int h = tid >> 5, e = tid & 31;
            const float* uu = &s_upd[h * HP];
            s_erase[h * MSZ + e] = sigmoidf_(uu[8 + e]);
            float kv = tanhf(uu[72 + e]);
            float ss = kv * kv;
            ss += __shfl_xor(ss, 1);
            ss += __shfl_xor(ss, 2);
            ss += __shfl_xor(ss, 4);
            ss += __shfl_xor(ss, 8);
            ss += __shfl_xor(ss, 16);
            s_khat[h * MSZ + e] = kv / (sqrtf(ss) + 1e-12f);
        }
        if (tid < NHEAD) {
            const float* uu = &s_upd[tid * HP];
            float a0 = softplusf_(uu[0]), a1 = softplusf_(uu[1]), a2 = softplusf_(uu[2]);
            float mx = fmaxf(a0, fmaxf(a1, a2));
            float e0 = expf(a0 - mx), e1 = expf(a1 - mx), e2 = expf(a2 - mx);
            float inv = 1.0f / (e0 + e1 + e2);
            s_shift[tid * 3 + 0] = e0 * inv;
            s_shift[tid * 3 + 1] = e1 * inv;
            s_shift[tid * 3 + 2] = e2 * inv;
            s_jd[tid] = sigmoidf_(uu[3]);
            float j0 = uu[4], j1 = uu[5], j2 = uu[6];
            float jm = fmaxf(j0, fmaxf(j1, j2));
            float f0 = expf(j0 - jm), f1 = expf(j1 - jm), f2 = expf(j2 - jm);
            float jinv = 1.0f / (f0 + f1 + f2);
            s_jmp[tid * 3 + 0] = f0 * jinv;
            s_jmp[tid * 3 + 1] = f1 * jinv;
            s_jmp[tid * 3 + 2] = f2 * jinv;
            s_gamma[tid] = 1.0f + softplusf_(uu[7]);
            s_beta[tid] = softplusf_(uu[104]);
            s_g[tid] = sigmoidf_(uu[105]);
        }
        __syncthreads();

        // ---- G: memory erase/add (uses OLD wt) ----
        #pragma unroll
        for (int r = 0; r < 8; ++r) {
            int idx = tid + (r << 10);
            int m = idx >> 8, n = idx & 255;
            float w0 = s_wt[0 * WTP + n], w1 = s_wt[1 * WTP + n];
            float w2 = s_wt[2 * WTP + n], w3 = s_wt[3 * WTP + n];
            float prod = (1.0f - s_erase[0 * MSZ + m] * w0) * (1.0f - s_erase[1 * MSZ + m] * w1)
                       * (1.0f - s_erase[2 * MSZ + m] * w2) * (1.0f - s_erase[3 * MSZ + m] * w3);
            float addv = s_upd[0 * HP + 40 + m] * w0 + s_upd[1 * HP + 40 + m] * w1
                       + s_upd[2 * HP + 40 + m] * w2 + s_upd[3 * HP + 40 + m] * w3;
            s_mem[m * MEMP + n] = s_mem[m * MEMP + n] * prod + addv;
        }
        __syncthreads();

        // ---- H: content logits with fused column norm ----
        {
            int h = tid >> 8, n = tid & 255;
            float ss = 0.0f, d = 0.0f;
            #pragma unroll 8
            for (int m = 0; m < MSZ; ++m) {
                float v = s_mem[m * MEMP + n];
                ss = fmaf(v, v, ss);
                d = fmaf(s_khat[h * MSZ + m], v, d);
            }
            s_logit[h * WTP + n] = s_beta[h] * d / (sqrtf(ss) + 1e-12f);
        }
        __syncthreads();

        // ---- I: per-head softmax reduce ----
        if (tid < 256) {
            int h = tid >> 6, lane = tid & 63;
            float mx = -1e30f;
            #pragma unroll
            for (int k = 0; k < 4; ++k) mx = fmaxf(mx, s_logit[h * WTP + lane + (k << 6)]);
            for (int m2 = 32; m2 >= 1; m2 >>= 1) mx = fmaxf(mx, __shfl_xor(mx, m2));
            float sm = 0.0f;
            #pragma unroll
            for (int k = 0; k < 4; ++k) sm += expf(s_logit[h * WTP + lane + (k << 6)] - mx);
            for (int m2 = 32; m2 >= 1; m2 >>= 1) sm += __shfl_xor(sm, m2);
            if (lane == 0) { s_smax[h] = mx; s_ssum[h] = sm; }
        }
        __syncthreads();

        // ---- J: gate (recomputed 3x, fused) + circular conv + sharpen ----
        {
            int h = tid >> 8, n = tid & 255;
            float gg = s_g[h], om = 1.0f - gg;
            float inv = 1.0f / s_ssum[h], mx = s_smax[h];
            int nm = (n + 255) & 255, np = (n + 1) & 255;
            float wgm = gg * expf(s_logit[h * WTP + nm] - mx) * inv + om * s_wt[h * WTP + nm];
            float wg0 = gg * expf(s_logit[h * WTP + n ] - mx) * inv + om * s_wt[h * WTP + n ];
            float wgp = gg * expf(s_logit[h * WTP + np] - mx) * inv + om * s_wt[h * WTP + np];
            float v = s_shift[h * 3 + 0] * wgm + s_shift[h * 3 + 1] * wg0 + s_shift[h * 3 + 2] * wgp;
            s_wts[h * WTP + n] = powf(v + 1e-12f, s_gamma[h]);
        }
        __syncthreads();

        // ---- K: sharpen-normalizer reduce ----
        if (tid < 256) {
            int h = tid >> 6, lane = tid & 63;
            float sm = 0.0f;
            #pragma unroll
            for (int k = 0; k < 4; ++k) sm += s_wts[h * WTP + lane + (k << 6)];
            for (int m2 = 32; m2 >= 1; m2 >>= 1) sm += __shfl_xor(sm, m2);
            if (lane == 0) s_psum[h] = sm;
        }
        __syncthreads();

        // ---- L: snapshot + jump; new wt, wt_dyn ----
        {
            int h = tid >> 8, n = tid & 255;
            float ws_ = s_wts[h * WTP + n] / s_psum[h];
            float jd = s_jd[h];
            float dyn = (1.0f - jd) * s_wtdyn[h * WTP + n] + jd * ws_;
            s_wtdyn[h * WTP + n] = dyn;
            float w0v = (n == 0) ? 1.0f : 0.0f;
            s_wt[h * WTP + n] = s_jmp[h * 3 + 0] * ws_ + s_jmp[h * 3 + 1] * dyn + s_jmp[h * 3 + 2] * w0v;
        }
        __syncthreads();
    }
}

extern "C" void kernel_launch(void* const* d_in, const int* in_sizes, int n_in,
                              void* d_out, int out_size, void* d_ws, size_t ws_size,
                              hipStream_t stream) {
    const float* x  = (const float*)d_in[0];
    const float* Wo = (const float*)d_in[1];
    const float* bo = (const float*)d_in[2];
    const float* Ws = (const float*)d_in[3];
    const float* bs = (const float*)d_in[4];
    const float* Wu = (const float*)d_in[5];
    const float* bu = (const float*)d_in[6];
    float* outp = (float*)d_out;
    __half* hW = (__half*)d_ws;   // 2,155,136 bytes

    int pack_blocks = (PACK_G4 + 255) / 256;
    hipLaunchKernelGGL(pack_w, dim3(pack_blocks), dim3(256), 0, stream, Ws, Wo, Wu, hW);
    hipLaunchKernelGGL(dwm_kernel, dim3(64), dim3(1024), SMEM_FLOATS * 4, stream,
                       x, (const __half*)hW, bo, bs, bu, outp);
}